// Round 1
// baseline (605.959 us; speedup 1.0000x reference)
//
#include <hip/hip_runtime.h>

// NodeEncoder: RoIAlign -> FC1(12544->512)+BN+ReLU -> FC2(512->512)+BN+ReLU -> max over K=8
// F=64 C=256 H=W=40, N=512 K=8 (R=4096), ROI=7, HID=D=512

typedef __bf16 bf16x8 __attribute__((ext_vector_type(8)));
typedef float f32x4 __attribute__((ext_vector_type(4)));

#define BN_EPS 1e-3f

__device__ __forceinline__ ushort f2bf(float f) {
  union { float f; unsigned u; } v; v.f = f;
  unsigned r = (v.u + 0x7FFFu + ((v.u >> 16) & 1u)) >> 16;
  return (ushort)r;
}
__device__ __forceinline__ float bf2f(ushort b) {
  union { unsigned u; float f; } v; v.u = ((unsigned)b) << 16;
  return v.f;
}
__device__ __forceinline__ void async16(const void* g, void* l) {
  __builtin_amdgcn_global_load_lds((const __attribute__((address_space(1))) void*)g,
                                   (__attribute__((address_space(3))) void*)l, 16, 0, 0);
}

// ---------------- 1. images [64,256,40,40] f32 -> imgT [64,40,40,256] f32 ----------------
__global__ __launch_bounds__(256) void transpose_kernel(const float* __restrict__ img,
                                                        float* __restrict__ imgT) {
  __shared__ float tile[256][41];  // +1 pad: LDS bank-conflict-free on strided read
  const int b = blockIdx.x;        // f*40 + y
  const int f = b / 40, y = b % 40;
  const int tid = threadIdx.x, wave = tid >> 6, lane = tid & 63;
  const float* src = img + (size_t)f * 256 * 1600 + y * 40;
  for (int c = wave; c < 256; c += 4)
    if (lane < 40) tile[c][lane] = src[(size_t)c * 1600 + lane];
  __syncthreads();
  float* dst = imgT + ((size_t)f * 1600 + y * 40) * 256;
#pragma unroll 4
  for (int x = 0; x < 40; ++x)
    dst[(size_t)x * 256 + tid] = tile[tid][x];  // coalesced 1KB stores
}

// ---------------- 2. w1 [512][256][49] f32 -> w1b [512][49*256] bf16 (k = p*256+c) -------
__global__ __launch_bounds__(256) void w1_convert(const float* __restrict__ w1,
                                                  ushort* __restrict__ w1b) {
  size_t i = (size_t)blockIdx.x * 256 + threadIdx.x;  // exactly 512*12544
  int o = (int)(i / 12544);
  int k = (int)(i % 12544);
  int p = k >> 8, c = k & 255;
  w1b[i] = f2bf(w1[(size_t)o * 12544 + c * 49 + p]);
}

__global__ __launch_bounds__(256) void w2_convert(const float* __restrict__ w2,
                                                  ushort* __restrict__ w2b) {
  size_t i = (size_t)blockIdx.x * 256 + threadIdx.x;  // exactly 512*512
  w2b[i] = f2bf(w2[i]);
}

// ---------------- 3. RoIAlign -> A [4096][12544] bf16, k = (py*7+px)*256 + c -------------
__global__ __launch_bounds__(256) void roi_kernel(const float* __restrict__ imgT,
                                                  const int* __restrict__ kf,
                                                  const float* __restrict__ boxes,
                                                  ushort* __restrict__ A) {
  __shared__ int sx0[49], sy0[49], sx1[49], sy1[49];
  __shared__ float sw00[49], sw01[49], sw10[49], sw11[49];
  __shared__ int sf;
  const int r = blockIdx.x, tid = threadIdx.x;
  if (tid == 0) sf = kf[r];
  if (tid < 49) {
    int py = tid / 7, px = tid % 7;
    float x1 = boxes[r * 4 + 0] * 40.f, y1 = boxes[r * 4 + 1] * 40.f;
    float x2 = boxes[r * 4 + 2] * 40.f, y2 = boxes[r * 4 + 3] * 40.f;
    float bw = (x2 - x1) * (1.f / 7.f), bh = (y2 - y1) * (1.f / 7.f);
    float X = x1 + (px + 0.5f) * bw, Y = y1 + (py + 0.5f) * bh;
    bool valid = (X > -1.f) && (X < 40.f) && (Y > -1.f) && (Y < 40.f);
    float x = fminf(fmaxf(X, 0.f), 39.f), y = fminf(fmaxf(Y, 0.f), 39.f);
    float x0f = floorf(x), y0f = floorf(y);
    int x0 = (int)x0f, y0 = (int)y0f;
    int x1i = min(x0 + 1, 39), y1i = min(y0 + 1, 39);
    float lx = x - x0f, ly = y - y0f;
    float vm = valid ? 1.f : 0.f;
    sx0[tid] = x0; sy0[tid] = y0; sx1[tid] = x1i; sy1[tid] = y1i;
    sw00[tid] = (1.f - ly) * (1.f - lx) * vm;
    sw01[tid] = (1.f - ly) * lx * vm;
    sw10[tid] = ly * (1.f - lx) * vm;
    sw11[tid] = ly * lx * vm;
  }
  __syncthreads();
  const int c4 = (tid & 63) * 4;  // 4 channels per thread
  const int pq = tid >> 6;        // position phase
  const float* base = imgT + (size_t)sf * 409600 + c4;
  ushort* outp = A + (size_t)r * 12544 + c4;
  for (int p = pq; p < 49; p += 4) {
    const float4 a = *(const float4*)(base + (size_t)(sy0[p] * 40 + sx0[p]) * 256);
    const float4 b = *(const float4*)(base + (size_t)(sy0[p] * 40 + sx1[p]) * 256);
    const float4 c = *(const float4*)(base + (size_t)(sy1[p] * 40 + sx0[p]) * 256);
    const float4 d = *(const float4*)(base + (size_t)(sy1[p] * 40 + sx1[p]) * 256);
    float w00 = sw00[p], w01 = sw01[p], w10 = sw10[p], w11 = sw11[p];
    ushort4 o;
    o.x = f2bf(a.x * w00 + b.x * w01 + c.x * w10 + d.x * w11);
    o.y = f2bf(a.y * w00 + b.y * w01 + c.y * w10 + d.y * w11);
    o.z = f2bf(a.z * w00 + b.z * w01 + c.z * w10 + d.z * w11);
    o.w = f2bf(a.w * w00 + b.w * w01 + c.w * w10 + d.w * w11);
    *(ushort4*)(outp + (size_t)p * 256) = o;
  }
}

// ---------------- 4. GEMM1: [4096,12544]x[512,12544]^T bf16, split-K=2, fp32 partials ----
__global__ __launch_bounds__(256) void gemm1_kernel(const ushort* __restrict__ A,
                                                    const ushort* __restrict__ B,
                                                    float* __restrict__ P) {
  constexpr int K = 12544;
  __shared__ __align__(16) ushort sA[128 * 32];
  __shared__ __align__(16) ushort sB[128 * 32];
  const int tid = threadIdx.x;
  const int lane = tid & 63, wave = tid >> 6;
  const int wm = wave >> 1, wn = wave & 1;
  const int r16 = lane & 15, quad = lane >> 4;
  const int r0 = blockIdx.x * 128, c0 = blockIdx.y * 128;
  const int kStart = blockIdx.z * (K / 2), kEnd = kStart + K / 2;
  const ushort* Ab = A + (size_t)r0 * K;
  const ushort* Bb = B + (size_t)c0 * K;
  const int row0 = tid >> 2;       // 0..63
  const int kq = (tid & 3) * 8;    // 16B sub-chunk within 32-wide K slice
  f32x4 acc[4][4] = {};
  for (int kk = kStart; kk < kEnd; kk += 32) {
    __syncthreads();
    async16(Ab + (size_t)row0 * K + kk + kq, (char*)sA + tid * 16);
    async16(Ab + (size_t)(row0 + 64) * K + kk + kq, (char*)sA + 4096 + tid * 16);
    async16(Bb + (size_t)row0 * K + kk + kq, (char*)sB + tid * 16);
    async16(Bb + (size_t)(row0 + 64) * K + kk + kq, (char*)sB + 4096 + tid * 16);
    __syncthreads();
    bf16x8 af[4], bfr[4];
#pragma unroll
    for (int i = 0; i < 4; ++i)
      af[i] = *(const bf16x8*)(sA + (wm * 64 + i * 16 + r16) * 32 + quad * 8);
#pragma unroll
    for (int j = 0; j < 4; ++j)
      bfr[j] = *(const bf16x8*)(sB + (wn * 64 + j * 16 + r16) * 32 + quad * 8);
#pragma unroll
    for (int i = 0; i < 4; ++i)
#pragma unroll
      for (int j = 0; j < 4; ++j)
        acc[i][j] = __builtin_amdgcn_mfma_f32_16x16x32_bf16(af[i], bfr[j], acc[i][j], 0, 0, 0);
  }
  float* Pz = P + ((size_t)blockIdx.z * 4096 + r0) * 512 + c0;
#pragma unroll
  for (int i = 0; i < 4; ++i)
#pragma unroll
    for (int j = 0; j < 4; ++j)
#pragma unroll
      for (int g = 0; g < 4; ++g)
        Pz[(size_t)(wm * 64 + i * 16 + quad * 4 + g) * 512 + (wn * 64 + j * 16 + r16)] =
            acc[i][j][g];
}

// ---------------- 5. combine split-K partials + b1 + BN1 + ReLU -> h1 bf16 ---------------
__global__ __launch_bounds__(256) void combine_kernel(const float* __restrict__ P,
                                                      const float* __restrict__ b1,
                                                      const float* __restrict__ g1,
                                                      const float* __restrict__ bt1,
                                                      const float* __restrict__ m1,
                                                      const float* __restrict__ v1,
                                                      ushort* __restrict__ h1) {
  size_t i = (size_t)blockIdx.x * 256 + threadIdx.x;  // exactly 4096*512
  int col = (int)(i & 511);
  float x = P[i] + P[i + 2097152];
  float s = g1[col] * rsqrtf(v1[col] + BN_EPS);
  float val = fmaxf((x + b1[col] - m1[col]) * s + bt1[col], 0.f);
  h1[i] = f2bf(val);
}

// ---------------- 6. GEMM2 + b2 + BN2 + ReLU + group-of-8 max -> out ---------------------
__global__ __launch_bounds__(256) void gemm2_kernel(const ushort* __restrict__ A,
                                                    const ushort* __restrict__ B,
                                                    const float* __restrict__ b2,
                                                    const float* __restrict__ g2,
                                                    const float* __restrict__ bt2,
                                                    const float* __restrict__ m2,
                                                    const float* __restrict__ v2,
                                                    float* __restrict__ out) {
  constexpr int K = 512;
  __shared__ __align__(16) ushort sA[128 * 32];
  __shared__ __align__(16) ushort sB[128 * 32];
  __shared__ ushort st[128 * 128];  // post-activation tile for group-max
  const int tid = threadIdx.x;
  const int lane = tid & 63, wave = tid >> 6;
  const int wm = wave >> 1, wn = wave & 1;
  const int r16 = lane & 15, quad = lane >> 4;
  const int r0 = blockIdx.x * 128, c0 = blockIdx.y * 128;
  const ushort* Ab = A + (size_t)r0 * K;
  const ushort* Bb = B + (size_t)c0 * K;
  const int row0 = tid >> 2;
  const int kq = (tid & 3) * 8;
  f32x4 acc[4][4] = {};
  for (int kk = 0; kk < K; kk += 32) {
    __syncthreads();
    async16(Ab + (size_t)row0 * K + kk + kq, (char*)sA + tid * 16);
    async16(Ab + (size_t)(row0 + 64) * K + kk + kq, (char*)sA + 4096 + tid * 16);
    async16(Bb + (size_t)row0 * K + kk + kq, (char*)sB + tid * 16);
    async16(Bb + (size_t)(row0 + 64) * K + kk + kq, (char*)sB + 4096 + tid * 16);
    __syncthreads();
    bf16x8 af[4], bfr[4];
#pragma unroll
    for (int i = 0; i < 4; ++i)
      af[i] = *(const bf16x8*)(sA + (wm * 64 + i * 16 + r16) * 32 + quad * 8);
#pragma unroll
    for (int j = 0; j < 4; ++j)
      bfr[j] = *(const bf16x8*)(sB + (wn * 64 + j * 16 + r16) * 32 + quad * 8);
#pragma unroll
    for (int i = 0; i < 4; ++i)
#pragma unroll
      for (int j = 0; j < 4; ++j)
        acc[i][j] = __builtin_amdgcn_mfma_f32_16x16x32_bf16(af[i], bfr[j], acc[i][j], 0, 0, 0);
  }
  // epilogue: bias + BN + relu, stage to LDS
  float ss[4], tt[4], bbv[4];
#pragma unroll
  for (int j = 0; j < 4; ++j) {
    int c = c0 + wn * 64 + j * 16 + r16;
    float s = g2[c] * rsqrtf(v2[c] + BN_EPS);
    ss[j] = s; tt[j] = bt2[c] - m2[c] * s; bbv[j] = b2[c];
  }
#pragma unroll
  for (int i = 0; i < 4; ++i)
#pragma unroll
    for (int j = 0; j < 4; ++j)
#pragma unroll
      for (int g = 0; g < 4; ++g) {
        int rr = wm * 64 + i * 16 + quad * 4 + g;
        int cc = wn * 64 + j * 16 + r16;
        float x = (acc[i][j][g] + bbv[j]) * ss[j] + tt[j];
        st[rr * 128 + cc] = f2bf(fmaxf(x, 0.f));
      }
  __syncthreads();
  // 128 rows = 16 complete groups of 8; reduce and store (no atomics needed)
  for (int e = tid; e < 2048; e += 256) {
    int gg = e >> 7, cc = e & 127;
    float m = 0.f;  // relu output >= 0, so 0 is the identity here
#pragma unroll
    for (int k = 0; k < 8; ++k) m = fmaxf(m, bf2f(st[(gg * 8 + k) * 128 + cc]));
    out[(size_t)(r0 / 8 + gg) * 512 + c0 + cc] = m;
  }
}

extern "C" void kernel_launch(void* const* d_in, const int* in_sizes, int n_in,
                              void* d_out, int out_size, void* d_ws, size_t ws_size,
                              hipStream_t stream) {
  (void)in_sizes; (void)n_in; (void)out_size; (void)ws_size;
  const float* images = (const float*)d_in[0];
  const int* kf      = (const int*)d_in[1];
  const float* boxes = (const float*)d_in[2];
  const float* w1    = (const float*)d_in[3];
  const float* b1    = (const float*)d_in[4];
  const float* g1    = (const float*)d_in[5];
  const float* bt1   = (const float*)d_in[6];
  const float* m1    = (const float*)d_in[7];
  const float* v1    = (const float*)d_in[8];
  const float* w2    = (const float*)d_in[9];
  const float* b2    = (const float*)d_in[10];
  const float* g2    = (const float*)d_in[11];
  const float* bt2   = (const float*)d_in[12];
  const float* m2    = (const float*)d_in[13];
  const float* v2    = (const float*)d_in[14];
  float* out = (float*)d_out;

  char* ws = (char*)d_ws;
  // layout (bytes):
  //   A    @ 0          : 4096*12544*2 = 102,760,448
  //   w1b  @ 102760448  : 512*12544*2  =  12,845,056
  //   w2b  @ 115605504  : 512*512*2    =     524,288
  //   imgT @ 116129792  : 64*40*40*256*4 = 104,857,600   (dead after roi_kernel)
  //   P    @ 116129792  : 2*4096*512*4 = 16,777,216      (aliases imgT — gemm1 runs after roi)
  //   h1   @ 132907008  : 4096*512*2   =  4,194,304
  ushort* Abuf = (ushort*)(ws + 0);
  ushort* w1b  = (ushort*)(ws + 102760448);
  ushort* w2b  = (ushort*)(ws + 115605504);
  float*  imgT = (float*)(ws + 116129792);
  float*  P    = (float*)(ws + 116129792);
  ushort* h1   = (ushort*)(ws + 132907008);

  hipLaunchKernelGGL(transpose_kernel, dim3(2560), dim3(256), 0, stream, images, imgT);
  hipLaunchKernelGGL(w1_convert, dim3(25088), dim3(256), 0, stream, w1, w1b);
  hipLaunchKernelGGL(w2_convert, dim3(1024), dim3(256), 0, stream, w2, w2b);
  hipLaunchKernelGGL(roi_kernel, dim3(4096), dim3(256), 0, stream, imgT, kf, boxes, Abuf);
  hipLaunchKernelGGL(gemm1_kernel, dim3(32, 4, 2), dim3(256), 0, stream, Abuf, w1b, P);
  hipLaunchKernelGGL(combine_kernel, dim3(8192), dim3(256), 0, stream, P, b1, g1, bt1, m1, v1, h1);
  hipLaunchKernelGGL(gemm2_kernel, dim3(32, 4), dim3(256), 0, stream, h1, w2b, b2, g2, bt2, m2, v2, out);
}

// Round 3
// 366.239 us; speedup vs baseline: 1.6545x; 1.6545x over previous
//
#include <hip/hip_runtime.h>

// NodeEncoder: RoIAlign -> FC1(12544->512)+BN+ReLU -> FC2(512->512)+BN+ReLU -> max over K=8
// F=64 C=256 H=W=40, N=512 K=8 (R=4096), ROI=7, HID=D=512

typedef __bf16 bf16x8 __attribute__((ext_vector_type(8)));
typedef float f32x4 __attribute__((ext_vector_type(4)));
typedef ushort us8v __attribute__((ext_vector_type(8)));

#define BN_EPS 1e-3f

__device__ __forceinline__ ushort f2bf(float f) {
  union { float f; unsigned u; } v; v.f = f;
  unsigned r = (v.u + 0x7FFFu + ((v.u >> 16) & 1u)) >> 16;
  return (ushort)r;
}
__device__ __forceinline__ float bf2f(ushort b) {
  union { unsigned u; float f; } v; v.u = ((unsigned)b) << 16;
  return v.f;
}
__device__ __forceinline__ void async16(const void* g, void* l) {
  __builtin_amdgcn_global_load_lds((const __attribute__((address_space(1))) void*)g,
                                   (__attribute__((address_space(3))) void*)l, 16, 0, 0);
}

// ------- 1. images [64,256,40,40] f32 -> imgTb [64,40,40,256] bf16, 64x64 LDS tile -------
__global__ __launch_bounds__(256) void transpose_kernel(const float* __restrict__ img,
                                                        ushort* __restrict__ imgTb) {
  __shared__ ushort lds[64 * 68];  // [pixel][channel], pitch 68
  const int f = blockIdx.x, c0 = blockIdx.y * 64, p0 = blockIdx.z * 64;
  const int tid = threadIdx.x;
  const float* src = img + (size_t)f * 409600 + (size_t)c0 * 1600 + p0;
#pragma unroll
  for (int it = 0; it < 4; ++it) {
    int idx = it * 256 + tid;
    int rc = idx >> 4;  // channel row 0..63
    int s = idx & 15;   // float4 group along pixels
    float4 v = *(const float4*)(src + (size_t)rc * 1600 + s * 4);
    int pp = s * 4;
    lds[(pp + 0) * 68 + rc] = f2bf(v.x);
    lds[(pp + 1) * 68 + rc] = f2bf(v.y);
    lds[(pp + 2) * 68 + rc] = f2bf(v.z);
    lds[(pp + 3) * 68 + rc] = f2bf(v.w);
  }
  __syncthreads();
  ushort* dst = imgTb + ((size_t)f * 1600 + p0) * 256 + c0;
#pragma unroll
  for (int it = 0; it < 4; ++it) {
    int idx = it * 256 + tid;
    int pp = idx >> 4;  // pixel row 0..63
    int sc = idx & 15;  // ushort4 group along channels
    ushort4 v;
    v.x = lds[pp * 68 + sc * 4 + 0];
    v.y = lds[pp * 68 + sc * 4 + 1];
    v.z = lds[pp * 68 + sc * 4 + 2];
    v.w = lds[pp * 68 + sc * 4 + 3];
    *(ushort4*)(dst + (size_t)pp * 256 + sc * 4) = v;
  }
}

// ------- 2. w1 [512][256][49] f32 -> w1b [512][49*256] bf16 (k = p*256+c), LDS staged ----
__global__ __launch_bounds__(256) void w1_convert(const float* __restrict__ w1,
                                                  ushort* __restrict__ w1b) {
  __shared__ float t[49 * 257];  // [p][c], pitch 257 floats
  const int o = blockIdx.x;
  const float* src = w1 + (size_t)o * 12544;
  for (int j = threadIdx.x; j < 12544; j += 256) {  // coalesced read, j = c*49+p
    int c = j / 49, p = j - c * 49;
    t[p * 257 + c] = src[j];
  }
  __syncthreads();
  ushort* dst = w1b + (size_t)o * 12544;
  for (int k = threadIdx.x; k < 12544; k += 256) {  // coalesced write, k = p*256+c
    int p = k >> 8, c = k & 255;
    dst[k] = f2bf(t[p * 257 + c]);
  }
}

__global__ __launch_bounds__(256) void w2_convert(const float* __restrict__ w2,
                                                  ushort* __restrict__ w2b) {
  size_t i = (size_t)blockIdx.x * 256 + threadIdx.x;  // exactly 512*512
  w2b[i] = f2bf(w2[i]);
}

// ------- 3. RoIAlign (bf16 image) -> A [4096][12544] bf16, k = (py*7+px)*256 + c ---------
__global__ __launch_bounds__(256) void roi_kernel(const ushort* __restrict__ imgTb,
                                                  const int* __restrict__ kf,
                                                  const float* __restrict__ boxes,
                                                  ushort* __restrict__ A) {
  __shared__ int sy0[49], sx0[49], sy1[49], sx1[49];
  __shared__ float sw00[49], sw01[49], sw10[49], sw11[49];
  __shared__ int sf;
  const int r = blockIdx.x, tid = threadIdx.x;
  if (tid == 0) sf = kf[r];
  if (tid < 49) {
    int py = tid / 7, px = tid % 7;
    float x1 = boxes[r * 4 + 0] * 40.f, y1 = boxes[r * 4 + 1] * 40.f;
    float x2 = boxes[r * 4 + 2] * 40.f, y2 = boxes[r * 4 + 3] * 40.f;
    float bw = (x2 - x1) * (1.f / 7.f), bh = (y2 - y1) * (1.f / 7.f);
    float X = x1 + (px + 0.5f) * bw, Y = y1 + (py + 0.5f) * bh;
    bool valid = (X > -1.f) && (X < 40.f) && (Y > -1.f) && (Y < 40.f);
    float x = fminf(fmaxf(X, 0.f), 39.f), y = fminf(fmaxf(Y, 0.f), 39.f);
    float x0f = floorf(x), y0f = floorf(y);
    int x0 = (int)x0f, y0 = (int)y0f;
    int x1i = min(x0 + 1, 39), y1i = min(y0 + 1, 39);
    float lx = x - x0f, ly = y - y0f;
    float vm = valid ? 1.f : 0.f;
    sx0[tid] = x0; sy0[tid] = y0; sx1[tid] = x1i; sy1[tid] = y1i;
    sw00[tid] = (1.f - ly) * (1.f - lx) * vm;
    sw01[tid] = (1.f - ly) * lx * vm;
    sw10[tid] = ly * (1.f - lx) * vm;
    sw11[tid] = ly * lx * vm;
  }
  __syncthreads();
  const int c8 = (tid & 31) * 8;  // 8 channels per thread (16B loads)
  const int pq = tid >> 5;        // position phase 0..7
  const ushort* base = imgTb + (size_t)sf * 409600 + c8;
  ushort* outp = A + (size_t)r * 12544 + c8;
  for (int p = pq; p < 49; p += 8) {
    const us8v a = *(const us8v*)(base + (size_t)(sy0[p] * 40 + sx0[p]) * 256);
    const us8v b = *(const us8v*)(base + (size_t)(sy0[p] * 40 + sx1[p]) * 256);
    const us8v c = *(const us8v*)(base + (size_t)(sy1[p] * 40 + sx0[p]) * 256);
    const us8v d = *(const us8v*)(base + (size_t)(sy1[p] * 40 + sx1[p]) * 256);
    float w00 = sw00[p], w01 = sw01[p], w10 = sw10[p], w11 = sw11[p];
    us8v o;
#pragma unroll
    for (int k = 0; k < 8; ++k)
      o[k] = f2bf(bf2f(a[k]) * w00 + bf2f(b[k]) * w01 + bf2f(c[k]) * w10 + bf2f(d[k]) * w11);
    *(us8v*)(outp + (size_t)p * 256) = o;
  }
}

// ------- 4. GEMM1: [4096,12544]x[512,12544]^T bf16, split-K=4, swizzled LDS -------------
__global__ __launch_bounds__(256) void gemm1_kernel(const ushort* __restrict__ A,
                                                    const ushort* __restrict__ B,
                                                    float* __restrict__ P) {
  constexpr int K = 12544;
  __shared__ __align__(16) ushort sA[128 * 32];
  __shared__ __align__(16) ushort sB[128 * 32];
  const int tid = threadIdx.x;
  const int lane = tid & 63, wave = tid >> 6;
  const int wm = wave >> 1, wn = wave & 1;
  const int r16 = lane & 15, quad = lane >> 4;
  const int r0 = blockIdx.x * 128, c0 = blockIdx.y * 128;
  const int kStart = blockIdx.z * (K / 4), kEnd = kStart + K / 4;
  const ushort* Ab = A + (size_t)r0 * K;
  const ushort* Bb = B + (size_t)c0 * K;
  const int row0 = tid >> 2;  // 0..63
  // XOR swizzle: LDS slot s of row R holds global chunk s ^ ((R>>1)&3)
  const int kq = (((tid & 3) ^ ((row0 >> 1) & 3))) * 8;
  // fragment read: global chunk `quad` for row R lives at slot quad^((R>>1)&3) = quad^((r16>>1)&3)
  const int qs = (quad ^ ((r16 >> 1) & 3)) * 8;
  f32x4 acc[4][4] = {};
  for (int kk = kStart; kk < kEnd; kk += 32) {
    __syncthreads();
    async16(Ab + (size_t)row0 * K + kk + kq, (char*)sA + tid * 16);
    async16(Ab + (size_t)(row0 + 64) * K + kk + kq, (char*)sA + 4096 + tid * 16);
    async16(Bb + (size_t)row0 * K + kk + kq, (char*)sB + tid * 16);
    async16(Bb + (size_t)(row0 + 64) * K + kk + kq, (char*)sB + 4096 + tid * 16);
    __syncthreads();
    bf16x8 af[4], bfr[4];
#pragma unroll
    for (int i = 0; i < 4; ++i)
      af[i] = *(const bf16x8*)(sA + (wm * 64 + i * 16 + r16) * 32 + qs);
#pragma unroll
    for (int j = 0; j < 4; ++j)
      bfr[j] = *(const bf16x8*)(sB + (wn * 64 + j * 16 + r16) * 32 + qs);
#pragma unroll
    for (int i = 0; i < 4; ++i)
#pragma unroll
      for (int j = 0; j < 4; ++j)
        acc[i][j] = __builtin_amdgcn_mfma_f32_16x16x32_bf16(af[i], bfr[j], acc[i][j], 0, 0, 0);
  }
  float* Pz = P + ((size_t)blockIdx.z * 4096 + r0) * 512 + c0;
#pragma unroll
  for (int i = 0; i < 4; ++i)
#pragma unroll
    for (int j = 0; j < 4; ++j)
#pragma unroll
      for (int g = 0; g < 4; ++g)
        Pz[(size_t)(wm * 64 + i * 16 + quad * 4 + g) * 512 + (wn * 64 + j * 16 + r16)] =
            acc[i][j][g];
}

// ------- 5. combine 4 split-K partials + b1 + BN1 + ReLU -> h1 bf16 ----------------------
__global__ __launch_bounds__(256) void combine_kernel(const float* __restrict__ P,
                                                      const float* __restrict__ b1,
                                                      const float* __restrict__ g1,
                                                      const float* __restrict__ bt1,
                                                      const float* __restrict__ m1,
                                                      const float* __restrict__ v1,
                                                      ushort* __restrict__ h1) {
  size_t i = (size_t)blockIdx.x * 256 + threadIdx.x;  // exactly 4096*512
  int col = (int)(i & 511);
  float x = P[i] + P[i + 2097152] + P[i + 2 * 2097152] + P[i + 3 * 2097152];
  float s = g1[col] * rsqrtf(v1[col] + BN_EPS);
  float val = fmaxf((x + b1[col] - m1[col]) * s + bt1[col], 0.f);
  h1[i] = f2bf(val);
}

// ------- 6. GEMM2 (64x128 tile) + b2 + BN2 + ReLU + group-of-8 max -> out ----------------
__global__ __launch_bounds__(256) void gemm2_kernel(const ushort* __restrict__ A,
                                                    const ushort* __restrict__ B,
                                                    const float* __restrict__ b2,
                                                    const float* __restrict__ g2,
                                                    const float* __restrict__ bt2,
                                                    const float* __restrict__ m2,
                                                    const float* __restrict__ v2,
                                                    float* __restrict__ out) {
  constexpr int K = 512;
  __shared__ __align__(16) ushort sA[64 * 32];   // 4096 B
  __shared__ __align__(16) ushort sB[128 * 32];  // 8192 B; row 64 starts at byte 4096
  __shared__ ushort st[64 * 128];  // post-activation tile for group-max
  const int tid = threadIdx.x;
  const int lane = tid & 63, wave = tid >> 6;
  const int wm = wave >> 1, wn = wave & 1;  // waves: 2 (rows) x 2 (cols)
  const int r16 = lane & 15, quad = lane >> 4;
  const int r0 = blockIdx.x * 64, c0 = blockIdx.y * 128;
  const ushort* Ab = A + (size_t)r0 * K;
  const ushort* Bb = B + (size_t)c0 * K;
  const int row0 = tid >> 2;
  const int kq = (((tid & 3) ^ ((row0 >> 1) & 3))) * 8;
  const int qs = (quad ^ ((r16 >> 1) & 3)) * 8;
  f32x4 acc[2][4] = {};
  for (int kk = 0; kk < K; kk += 32) {
    __syncthreads();
    async16(Ab + (size_t)row0 * K + kk + kq, (char*)sA + tid * 16);
    async16(Bb + (size_t)row0 * K + kk + kq, (char*)sB + tid * 16);
    // FIX (R2 bug): rows 64..127 of sB live at byte 4096, not 2048
    async16(Bb + (size_t)(row0 + 64) * K + kk + kq, (char*)sB + 4096 + tid * 16);
    __syncthreads();
    bf16x8 af[2], bfr[4];
#pragma unroll
    for (int i = 0; i < 2; ++i)
      af[i] = *(const bf16x8*)(sA + (wm * 32 + i * 16 + r16) * 32 + qs);
#pragma unroll
    for (int j = 0; j < 4; ++j)
      bfr[j] = *(const bf16x8*)(sB + (wn * 64 + j * 16 + r16) * 32 + qs);
#pragma unroll
    for (int i = 0; i < 2; ++i)
#pragma unroll
      for (int j = 0; j < 4; ++j)
        acc[i][j] = __builtin_amdgcn_mfma_f32_16x16x32_bf16(af[i], bfr[j], acc[i][j], 0, 0, 0);
  }
  // epilogue: bias + BN + relu, stage to LDS
  float ss[4], tt[4], bbv[4];
#pragma unroll
  for (int j = 0; j < 4; ++j) {
    int c = c0 + wn * 64 + j * 16 + r16;
    float s = g2[c] * rsqrtf(v2[c] + BN_EPS);
    ss[j] = s; tt[j] = bt2[c] - m2[c] * s; bbv[j] = b2[c];
  }
#pragma unroll
  for (int i = 0; i < 2; ++i)
#pragma unroll
    for (int j = 0; j < 4; ++j)
#pragma unroll
      for (int g = 0; g < 4; ++g) {
        int rr = wm * 32 + i * 16 + quad * 4 + g;
        int cc = wn * 64 + j * 16 + r16;
        float x = (acc[i][j][g] + bbv[j]) * ss[j] + tt[j];
        st[rr * 128 + cc] = f2bf(fmaxf(x, 0.f));
      }
  __syncthreads();
  // 64 rows = 8 complete groups of 8; reduce and store (no atomics)
  for (int e = tid; e < 1024; e += 256) {
    int gg = e >> 7, cc = e & 127;
    float m = 0.f;  // relu output >= 0
#pragma unroll
    for (int k = 0; k < 8; ++k) m = fmaxf(m, bf2f(st[(gg * 8 + k) * 128 + cc]));
    out[(size_t)(r0 / 8 + gg) * 512 + c0 + cc] = m;
  }
}

extern "C" void kernel_launch(void* const* d_in, const int* in_sizes, int n_in,
                              void* d_out, int out_size, void* d_ws, size_t ws_size,
                              hipStream_t stream) {
  (void)in_sizes; (void)n_in; (void)out_size; (void)ws_size;
  const float* images = (const float*)d_in[0];
  const int* kf      = (const int*)d_in[1];
  const float* boxes = (const float*)d_in[2];
  const float* w1    = (const float*)d_in[3];
  const float* b1    = (const float*)d_in[4];
  const float* g1    = (const float*)d_in[5];
  const float* bt1   = (const float*)d_in[6];
  const float* m1    = (const float*)d_in[7];
  const float* v1    = (const float*)d_in[8];
  const float* w2    = (const float*)d_in[9];
  const float* b2    = (const float*)d_in[10];
  const float* g2    = (const float*)d_in[11];
  const float* bt2   = (const float*)d_in[12];
  const float* m2    = (const float*)d_in[13];
  const float* v2    = (const float*)d_in[14];
  float* out = (float*)d_out;

  char* ws = (char*)d_ws;
  // layout (bytes):  [ws_size >= 221 MB proven in round 1]
  //   A     @ 0          : 4096*12544*2 = 102,760,448
  //   w1b   @ 102,760,448: 512*12544*2  =  12,845,056
  //   w2b   @ 115,605,504: 512*512*2    =     524,288
  //   imgTb @ 116,129,792: 64*1600*256*2 = 52,428,800   (dead after roi_kernel)
  //   P     @ 116,129,792: 4*4096*512*4 = 33,554,432    (aliases imgTb)
  //   h1    @ 149,684,224: 4096*512*2   =  4,194,304    (after P)
  ushort* Abuf  = (ushort*)(ws + 0);
  ushort* w1b   = (ushort*)(ws + 102760448);
  ushort* w2b   = (ushort*)(ws + 115605504);
  ushort* imgTb = (ushort*)(ws + 116129792);
  float*  P     = (float*)(ws + 116129792);
  ushort* h1    = (ushort*)(ws + 149684224);

  hipLaunchKernelGGL(transpose_kernel, dim3(64, 4, 25), dim3(256), 0, stream, images, imgTb);
  hipLaunchKernelGGL(w1_convert, dim3(512), dim3(256), 0, stream, w1, w1b);
  hipLaunchKernelGGL(w2_convert, dim3(1024), dim3(256), 0, stream, w2, w2b);
  hipLaunchKernelGGL(roi_kernel, dim3(4096), dim3(256), 0, stream, imgTb, kf, boxes, Abuf);
  hipLaunchKernelGGL(gemm1_kernel, dim3(32, 4, 4), dim3(256), 0, stream, Abuf, w1b, P);
  hipLaunchKernelGGL(combine_kernel, dim3(8192), dim3(256), 0, stream, P, b1, g1, bt1, m1, v1, h1);
  hipLaunchKernelGGL(gemm2_kernel, dim3(64, 4), dim3(256), 0, stream, h1, w2b, b2, g2, bt2, m2, v2, out);
}

// Round 4
// 364.746 us; speedup vs baseline: 1.6613x; 1.0041x over previous
//
#include <hip/hip_runtime.h>

// NodeEncoder: RoIAlign -> FC1(12544->512)+BN+ReLU -> FC2(512->512)+BN+ReLU -> max over K=8
// F=64 C=256 H=W=40, N=512 K=8 (R=4096), ROI=7, HID=D=512

typedef __bf16 bf16x8 __attribute__((ext_vector_type(8)));
typedef float f32x4 __attribute__((ext_vector_type(4)));
typedef ushort us8v __attribute__((ext_vector_type(8)));

#define BN_EPS 1e-3f

__device__ __forceinline__ ushort f2bf(float f) {
  union { float f; unsigned u; } v; v.f = f;
  unsigned r = (v.u + 0x7FFFu + ((v.u >> 16) & 1u)) >> 16;
  return (ushort)r;
}
__device__ __forceinline__ float bf2f(ushort b) {
  union { unsigned u; float f; } v; v.u = ((unsigned)b) << 16;
  return v.f;
}
__device__ __forceinline__ void async16(const void* g, void* l) {
  __builtin_amdgcn_global_load_lds((const __attribute__((address_space(1))) void*)g,
                                   (__attribute__((address_space(3))) void*)l, 16, 0, 0);
}

// ------- 1. images [64,256,40,40] f32 -> imgTb [64,40,40,256] bf16, 64x64 LDS tile -------
__global__ __launch_bounds__(256) void transpose_kernel(const float* __restrict__ img,
                                                        ushort* __restrict__ imgTb) {
  __shared__ ushort lds[64 * 68];  // [pixel][channel], pitch 68
  const int f = blockIdx.x, c0 = blockIdx.y * 64, p0 = blockIdx.z * 64;
  const int tid = threadIdx.x;
  const float* src = img + (size_t)f * 409600 + (size_t)c0 * 1600 + p0;
#pragma unroll
  for (int it = 0; it < 4; ++it) {
    int idx = it * 256 + tid;
    int rc = idx >> 4;  // channel row 0..63
    int s = idx & 15;   // float4 group along pixels
    float4 v = *(const float4*)(src + (size_t)rc * 1600 + s * 4);
    int pp = s * 4;
    lds[(pp + 0) * 68 + rc] = f2bf(v.x);
    lds[(pp + 1) * 68 + rc] = f2bf(v.y);
    lds[(pp + 2) * 68 + rc] = f2bf(v.z);
    lds[(pp + 3) * 68 + rc] = f2bf(v.w);
  }
  __syncthreads();
  ushort* dst = imgTb + ((size_t)f * 1600 + p0) * 256 + c0;
#pragma unroll
  for (int it = 0; it < 4; ++it) {
    int idx = it * 256 + tid;
    int pp = idx >> 4;  // pixel row 0..63
    int sc = idx & 15;  // ushort4 group along channels
    ushort4 v;
    v.x = lds[pp * 68 + sc * 4 + 0];
    v.y = lds[pp * 68 + sc * 4 + 1];
    v.z = lds[pp * 68 + sc * 4 + 2];
    v.w = lds[pp * 68 + sc * 4 + 3];
    *(ushort4*)(dst + (size_t)pp * 256 + sc * 4) = v;
  }
}

// ------- 2. w1 [512][256][49] f32 -> w1b [512][49*256] bf16 (k = p*256+c), LDS staged ----
__global__ __launch_bounds__(256) void w1_convert(const float* __restrict__ w1,
                                                  ushort* __restrict__ w1b) {
  __shared__ float t[49 * 257];  // [p][c], pitch 257 floats
  const int o = blockIdx.x;
  const float* src = w1 + (size_t)o * 12544;
  for (int j = threadIdx.x; j < 12544; j += 256) {  // coalesced read, j = c*49+p
    int c = j / 49, p = j - c * 49;
    t[p * 257 + c] = src[j];
  }
  __syncthreads();
  ushort* dst = w1b + (size_t)o * 12544;
  for (int k = threadIdx.x; k < 12544; k += 256) {  // coalesced write, k = p*256+c
    int p = k >> 8, c = k & 255;
    dst[k] = f2bf(t[p * 257 + c]);
  }
}

__global__ __launch_bounds__(256) void w2_convert(const float* __restrict__ w2,
                                                  ushort* __restrict__ w2b) {
  size_t i = (size_t)blockIdx.x * 256 + threadIdx.x;  // exactly 512*512
  w2b[i] = f2bf(w2[i]);
}

// ------- 3. RoIAlign (bf16 image) -> A [4096][12544] bf16, k = (py*7+px)*256 + c ---------
__global__ __launch_bounds__(256) void roi_kernel(const ushort* __restrict__ imgTb,
                                                  const int* __restrict__ kf,
                                                  const float* __restrict__ boxes,
                                                  ushort* __restrict__ A) {
  __shared__ int sy0[49], sx0[49], sy1[49], sx1[49];
  __shared__ float sw00[49], sw01[49], sw10[49], sw11[49];
  __shared__ int sf;
  const int r = blockIdx.x, tid = threadIdx.x;
  if (tid == 0) sf = kf[r];
  if (tid < 49) {
    int py = tid / 7, px = tid % 7;
    float x1 = boxes[r * 4 + 0] * 40.f, y1 = boxes[r * 4 + 1] * 40.f;
    float x2 = boxes[r * 4 + 2] * 40.f, y2 = boxes[r * 4 + 3] * 40.f;
    float bw = (x2 - x1) * (1.f / 7.f), bh = (y2 - y1) * (1.f / 7.f);
    float X = x1 + (px + 0.5f) * bw, Y = y1 + (py + 0.5f) * bh;
    bool valid = (X > -1.f) && (X < 40.f) && (Y > -1.f) && (Y < 40.f);
    float x = fminf(fmaxf(X, 0.f), 39.f), y = fminf(fmaxf(Y, 0.f), 39.f);
    float x0f = floorf(x), y0f = floorf(y);
    int x0 = (int)x0f, y0 = (int)y0f;
    int x1i = min(x0 + 1, 39), y1i = min(y0 + 1, 39);
    float lx = x - x0f, ly = y - y0f;
    float vm = valid ? 1.f : 0.f;
    sx0[tid] = x0; sy0[tid] = y0; sx1[tid] = x1i; sy1[tid] = y1i;
    sw00[tid] = (1.f - ly) * (1.f - lx) * vm;
    sw01[tid] = (1.f - ly) * lx * vm;
    sw10[tid] = ly * (1.f - lx) * vm;
    sw11[tid] = ly * lx * vm;
  }
  __syncthreads();
  const int c8 = (tid & 31) * 8;  // 8 channels per thread (16B loads)
  const int pq = tid >> 5;        // position phase 0..7
  const ushort* base = imgTb + (size_t)sf * 409600 + c8;
  ushort* outp = A + (size_t)r * 12544 + c8;
  for (int p = pq; p < 49; p += 8) {
    const us8v a = *(const us8v*)(base + (size_t)(sy0[p] * 40 + sx0[p]) * 256);
    const us8v b = *(const us8v*)(base + (size_t)(sy0[p] * 40 + sx1[p]) * 256);
    const us8v c = *(const us8v*)(base + (size_t)(sy1[p] * 40 + sx0[p]) * 256);
    const us8v d = *(const us8v*)(base + (size_t)(sy1[p] * 40 + sx1[p]) * 256);
    float w00 = sw00[p], w01 = sw01[p], w10 = sw10[p], w11 = sw11[p];
    us8v o;
#pragma unroll
    for (int k = 0; k < 8; ++k)
      o[k] = f2bf(bf2f(a[k]) * w00 + bf2f(b[k]) * w01 + bf2f(c[k]) * w10 + bf2f(d[k]) * w11);
    *(us8v*)(outp + (size_t)p * 256) = o;
  }
}

// ------- 4. GEMM1: [4096,12544]x[512,12544]^T bf16, split-K=8, bf16 partials -------------
__global__ __launch_bounds__(256) void gemm1_kernel(const ushort* __restrict__ A,
                                                    const ushort* __restrict__ B,
                                                    ushort* __restrict__ P) {
  constexpr int K = 12544;
  __shared__ __align__(16) ushort sA[128 * 32];
  __shared__ __align__(16) ushort sB[128 * 32];
  const int tid = threadIdx.x;
  const int lane = tid & 63, wave = tid >> 6;
  const int wm = wave >> 1, wn = wave & 1;
  const int r16 = lane & 15, quad = lane >> 4;
  const int r0 = blockIdx.x * 128, c0 = blockIdx.y * 128;
  const int kStart = blockIdx.z * (K / 8), kEnd = kStart + K / 8;  // 1568 = 49 iters
  const ushort* Ab = A + (size_t)r0 * K;
  const ushort* Bb = B + (size_t)c0 * K;
  const int row0 = tid >> 2;  // 0..63
  // XOR swizzle: LDS slot s of row R holds global chunk s ^ ((R>>1)&3)
  const int kq = (((tid & 3) ^ ((row0 >> 1) & 3))) * 8;
  const int qs = (quad ^ ((r16 >> 1) & 3)) * 8;
  f32x4 acc[4][4] = {};
  for (int kk = kStart; kk < kEnd; kk += 32) {
    __syncthreads();
    async16(Ab + (size_t)row0 * K + kk + kq, (char*)sA + tid * 16);
    async16(Ab + (size_t)(row0 + 64) * K + kk + kq, (char*)sA + 4096 + tid * 16);
    async16(Bb + (size_t)row0 * K + kk + kq, (char*)sB + tid * 16);
    async16(Bb + (size_t)(row0 + 64) * K + kk + kq, (char*)sB + 4096 + tid * 16);
    __syncthreads();
    bf16x8 af[4], bfr[4];
#pragma unroll
    for (int i = 0; i < 4; ++i)
      af[i] = *(const bf16x8*)(sA + (wm * 64 + i * 16 + r16) * 32 + qs);
#pragma unroll
    for (int j = 0; j < 4; ++j)
      bfr[j] = *(const bf16x8*)(sB + (wn * 64 + j * 16 + r16) * 32 + qs);
#pragma unroll
    for (int i = 0; i < 4; ++i)
#pragma unroll
      for (int j = 0; j < 4; ++j)
        acc[i][j] = __builtin_amdgcn_mfma_f32_16x16x32_bf16(af[i], bfr[j], acc[i][j], 0, 0, 0);
  }
  ushort* Pz = P + ((size_t)blockIdx.z * 4096 + r0) * 512 + c0;
#pragma unroll
  for (int i = 0; i < 4; ++i)
#pragma unroll
    for (int j = 0; j < 4; ++j)
#pragma unroll
      for (int g = 0; g < 4; ++g)
        Pz[(size_t)(wm * 64 + i * 16 + quad * 4 + g) * 512 + (wn * 64 + j * 16 + r16)] =
            f2bf(acc[i][j][g]);
  }

// ------- 5. combine 8 split-K bf16 partials + b1 + BN1 + ReLU -> h1 bf16 -----------------
__global__ __launch_bounds__(256) void combine_kernel(const ushort* __restrict__ P,
                                                      const float* __restrict__ b1,
                                                      const float* __restrict__ g1,
                                                      const float* __restrict__ bt1,
                                                      const float* __restrict__ m1,
                                                      const float* __restrict__ v1,
                                                      ushort* __restrict__ h1) {
  size_t i = (size_t)blockIdx.x * 256 + threadIdx.x;  // exactly 4096*512
  int col = (int)(i & 511);
  float x = 0.f;
#pragma unroll
  for (int z = 0; z < 8; ++z) x += bf2f(P[i + (size_t)z * 2097152]);
  float s = g1[col] * rsqrtf(v1[col] + BN_EPS);
  float val = fmaxf((x + b1[col] - m1[col]) * s + bt1[col], 0.f);
  h1[i] = f2bf(val);
}

// ------- 6. GEMM2 (64x128 tile) + b2 + BN2 + ReLU + group-of-8 max -> out ----------------
__global__ __launch_bounds__(256) void gemm2_kernel(const ushort* __restrict__ A,
                                                    const ushort* __restrict__ B,
                                                    const float* __restrict__ b2,
                                                    const float* __restrict__ g2,
                                                    const float* __restrict__ bt2,
                                                    const float* __restrict__ m2,
                                                    const float* __restrict__ v2,
                                                    float* __restrict__ out) {
  constexpr int K = 512;
  __shared__ __align__(16) ushort sA[64 * 32];   // 4096 B
  __shared__ __align__(16) ushort sB[128 * 32];  // 8192 B; row 64 starts at byte 4096
  __shared__ ushort st[64 * 128];  // post-activation tile for group-max
  const int tid = threadIdx.x;
  const int lane = tid & 63, wave = tid >> 6;
  const int wm = wave >> 1, wn = wave & 1;  // waves: 2 (rows) x 2 (cols)
  const int r16 = lane & 15, quad = lane >> 4;
  const int r0 = blockIdx.x * 64, c0 = blockIdx.y * 128;
  const ushort* Ab = A + (size_t)r0 * K;
  const ushort* Bb = B + (size_t)c0 * K;
  const int row0 = tid >> 2;
  const int kq = (((tid & 3) ^ ((row0 >> 1) & 3))) * 8;
  const int qs = (quad ^ ((r16 >> 1) & 3)) * 8;
  f32x4 acc[2][4] = {};
  for (int kk = 0; kk < K; kk += 32) {
    __syncthreads();
    async16(Ab + (size_t)row0 * K + kk + kq, (char*)sA + tid * 16);
    async16(Bb + (size_t)row0 * K + kk + kq, (char*)sB + tid * 16);
    async16(Bb + (size_t)(row0 + 64) * K + kk + kq, (char*)sB + 4096 + tid * 16);
    __syncthreads();
    bf16x8 af[2], bfr[4];
#pragma unroll
    for (int i = 0; i < 2; ++i)
      af[i] = *(const bf16x8*)(sA + (wm * 32 + i * 16 + r16) * 32 + qs);
#pragma unroll
    for (int j = 0; j < 4; ++j)
      bfr[j] = *(const bf16x8*)(sB + (wn * 64 + j * 16 + r16) * 32 + qs);
#pragma unroll
    for (int i = 0; i < 2; ++i)
#pragma unroll
      for (int j = 0; j < 4; ++j)
        acc[i][j] = __builtin_amdgcn_mfma_f32_16x16x32_bf16(af[i], bfr[j], acc[i][j], 0, 0, 0);
  }
  // epilogue: bias + BN + relu, stage to LDS
  float ss[4], tt[4], bbv[4];
#pragma unroll
  for (int j = 0; j < 4; ++j) {
    int c = c0 + wn * 64 + j * 16 + r16;
    float s = g2[c] * rsqrtf(v2[c] + BN_EPS);
    ss[j] = s; tt[j] = bt2[c] - m2[c] * s; bbv[j] = b2[c];
  }
#pragma unroll
  for (int i = 0; i < 2; ++i)
#pragma unroll
    for (int j = 0; j < 4; ++j)
#pragma unroll
      for (int g = 0; g < 4; ++g) {
        int rr = wm * 32 + i * 16 + quad * 4 + g;
        int cc = wn * 64 + j * 16 + r16;
        float x = (acc[i][j][g] + bbv[j]) * ss[j] + tt[j];
        st[rr * 128 + cc] = f2bf(fmaxf(x, 0.f));
      }
  __syncthreads();
  // 64 rows = 8 complete groups of 8; reduce and store (no atomics)
  for (int e = tid; e < 1024; e += 256) {
    int gg = e >> 7, cc = e & 127;
    float m = 0.f;  // relu output >= 0
#pragma unroll
    for (int k = 0; k < 8; ++k) m = fmaxf(m, bf2f(st[(gg * 8 + k) * 128 + cc]));
    out[(size_t)(r0 / 8 + gg) * 512 + c0 + cc] = m;
  }
}

extern "C" void kernel_launch(void* const* d_in, const int* in_sizes, int n_in,
                              void* d_out, int out_size, void* d_ws, size_t ws_size,
                              hipStream_t stream) {
  (void)in_sizes; (void)n_in; (void)out_size; (void)ws_size;
  const float* images = (const float*)d_in[0];
  const int* kf      = (const int*)d_in[1];
  const float* boxes = (const float*)d_in[2];
  const float* w1    = (const float*)d_in[3];
  const float* b1    = (const float*)d_in[4];
  const float* g1    = (const float*)d_in[5];
  const float* bt1   = (const float*)d_in[6];
  const float* m1    = (const float*)d_in[7];
  const float* v1    = (const float*)d_in[8];
  const float* w2    = (const float*)d_in[9];
  const float* b2    = (const float*)d_in[10];
  const float* g2    = (const float*)d_in[11];
  const float* bt2   = (const float*)d_in[12];
  const float* m2    = (const float*)d_in[13];
  const float* v2    = (const float*)d_in[14];
  float* out = (float*)d_out;

  char* ws = (char*)d_ws;
  // layout (bytes):  [ws_size >= 221 MB proven in round 1]
  //   A     @ 0          : 4096*12544*2 = 102,760,448
  //   w1b   @ 102,760,448: 512*12544*2  =  12,845,056
  //   w2b   @ 115,605,504: 512*512*2    =     524,288
  //   imgTb @ 116,129,792: 64*1600*256*2 = 52,428,800   (dead after roi_kernel)
  //   P     @ 116,129,792: 8*4096*512*2 = 33,554,432    (bf16 partials, aliases imgTb)
  //   h1    @ 149,684,224: 4096*512*2   =  4,194,304
  ushort* Abuf  = (ushort*)(ws + 0);
  ushort* w1b   = (ushort*)(ws + 102760448);
  ushort* w2b   = (ushort*)(ws + 115605504);
  ushort* imgTb = (ushort*)(ws + 116129792);
  ushort* P     = (ushort*)(ws + 116129792);
  ushort* h1    = (ushort*)(ws + 149684224);

  hipLaunchKernelGGL(transpose_kernel, dim3(64, 4, 25), dim3(256), 0, stream, images, imgTb);
  hipLaunchKernelGGL(w1_convert, dim3(512), dim3(256), 0, stream, w1, w1b);
  hipLaunchKernelGGL(w2_convert, dim3(1024), dim3(256), 0, stream, w2, w2b);
  hipLaunchKernelGGL(roi_kernel, dim3(4096), dim3(256), 0, stream, imgTb, kf, boxes, Abuf);
  hipLaunchKernelGGL(gemm1_kernel, dim3(32, 4, 8), dim3(256), 0, stream, Abuf, w1b, P);
  hipLaunchKernelGGL(combine_kernel, dim3(8192), dim3(256), 0, stream, P, b1, g1, bt1, m1, v1, h1);
  hipLaunchKernelGGL(gemm2_kernel, dim3(64, 4), dim3(256), 0, stream, h1, w2b, b2, g2, bt2, m2, v2, out);
}

// Round 5
// 356.396 us; speedup vs baseline: 1.7002x; 1.0234x over previous
//
#include <hip/hip_runtime.h>

// NodeEncoder: RoIAlign -> FC1(12544->512)+BN+ReLU -> FC2(512->512)+BN+ReLU -> max over K=8
// F=64 C=256 H=W=40, N=512 K=8 (R=4096), ROI=7, HID=D=512

typedef __bf16 bf16x8 __attribute__((ext_vector_type(8)));
typedef float f32x4 __attribute__((ext_vector_type(4)));
typedef ushort us8v __attribute__((ext_vector_type(8)));

#define BN_EPS 1e-3f

__device__ __forceinline__ ushort f2bf(float f) {
  union { float f; unsigned u; } v; v.f = f;
  unsigned r = (v.u + 0x7FFFu + ((v.u >> 16) & 1u)) >> 16;
  return (ushort)r;
}
__device__ __forceinline__ float bf2f(ushort b) {
  union { unsigned u; float f; } v; v.u = ((unsigned)b) << 16;
  return v.f;
}
__device__ __forceinline__ void async16(const void* g, void* l) {
  __builtin_amdgcn_global_load_lds((const __attribute__((address_space(1))) void*)g,
                                   (__attribute__((address_space(3))) void*)l, 16, 0, 0);
}

// ------- 1. images [64,256,40,40] f32 -> imgTb [64,40,40,256] bf16, 64x64 LDS tile -------
__global__ __launch_bounds__(256) void transpose_kernel(const float* __restrict__ img,
                                                        ushort* __restrict__ imgTb) {
  __shared__ ushort lds[64 * 68];  // [pixel][channel], pitch 68
  const int f = blockIdx.x, c0 = blockIdx.y * 64, p0 = blockIdx.z * 64;
  const int tid = threadIdx.x;
  const float* src = img + (size_t)f * 409600 + (size_t)c0 * 1600 + p0;
#pragma unroll
  for (int it = 0; it < 4; ++it) {
    int idx = it * 256 + tid;
    int rc = idx >> 4;  // channel row 0..63
    int s = idx & 15;   // float4 group along pixels
    float4 v = *(const float4*)(src + (size_t)rc * 1600 + s * 4);
    int pp = s * 4;
    lds[(pp + 0) * 68 + rc] = f2bf(v.x);
    lds[(pp + 1) * 68 + rc] = f2bf(v.y);
    lds[(pp + 2) * 68 + rc] = f2bf(v.z);
    lds[(pp + 3) * 68 + rc] = f2bf(v.w);
  }
  __syncthreads();
  ushort* dst = imgTb + ((size_t)f * 1600 + p0) * 256 + c0;
#pragma unroll
  for (int it = 0; it < 4; ++it) {
    int idx = it * 256 + tid;
    int pp = idx >> 4;  // pixel row 0..63
    int sc = idx & 15;  // ushort4 group along channels
    ushort4 v;
    v.x = lds[pp * 68 + sc * 4 + 0];
    v.y = lds[pp * 68 + sc * 4 + 1];
    v.z = lds[pp * 68 + sc * 4 + 2];
    v.w = lds[pp * 68 + sc * 4 + 3];
    *(ushort4*)(dst + (size_t)pp * 256 + sc * 4) = v;
  }
}

// ------- 2. w1 [512][256][49] f32 -> w1b [512][49*256] bf16 (k = p*256+c), LDS staged ----
__global__ __launch_bounds__(256) void w1_convert(const float* __restrict__ w1,
                                                  ushort* __restrict__ w1b) {
  __shared__ float t[49 * 257];  // [p][c], pitch 257 floats
  const int o = blockIdx.x;
  const float* src = w1 + (size_t)o * 12544;
  for (int j = threadIdx.x; j < 12544; j += 256) {  // coalesced read, j = c*49+p
    int c = j / 49, p = j - c * 49;
    t[p * 257 + c] = src[j];
  }
  __syncthreads();
  ushort* dst = w1b + (size_t)o * 12544;
  for (int k = threadIdx.x; k < 12544; k += 256) {  // coalesced write, k = p*256+c
    int p = k >> 8, c = k & 255;
    dst[k] = f2bf(t[p * 257 + c]);
  }
}

__global__ __launch_bounds__(256) void w2_convert(const float* __restrict__ w2,
                                                  ushort* __restrict__ w2b) {
  size_t i = (size_t)blockIdx.x * 256 + threadIdx.x;  // exactly 512*512
  w2b[i] = f2bf(w2[i]);
}

// ------- 3. RoIAlign (bf16 image) -> A [4096][12544] bf16, k = (py*7+px)*256 + c ---------
__global__ __launch_bounds__(256) void roi_kernel(const ushort* __restrict__ imgTb,
                                                  const int* __restrict__ kf,
                                                  const float* __restrict__ boxes,
                                                  ushort* __restrict__ A) {
  __shared__ int sy0[49], sx0[49], sy1[49], sx1[49];
  __shared__ float sw00[49], sw01[49], sw10[49], sw11[49];
  __shared__ int sf;
  const int r = blockIdx.x, tid = threadIdx.x;
  if (tid == 0) sf = kf[r];
  if (tid < 49) {
    int py = tid / 7, px = tid % 7;
    float x1 = boxes[r * 4 + 0] * 40.f, y1 = boxes[r * 4 + 1] * 40.f;
    float x2 = boxes[r * 4 + 2] * 40.f, y2 = boxes[r * 4 + 3] * 40.f;
    float bw = (x2 - x1) * (1.f / 7.f), bh = (y2 - y1) * (1.f / 7.f);
    float X = x1 + (px + 0.5f) * bw, Y = y1 + (py + 0.5f) * bh;
    bool valid = (X > -1.f) && (X < 40.f) && (Y > -1.f) && (Y < 40.f);
    float x = fminf(fmaxf(X, 0.f), 39.f), y = fminf(fmaxf(Y, 0.f), 39.f);
    float x0f = floorf(x), y0f = floorf(y);
    int x0 = (int)x0f, y0 = (int)y0f;
    int x1i = min(x0 + 1, 39), y1i = min(y0 + 1, 39);
    float lx = x - x0f, ly = y - y0f;
    float vm = valid ? 1.f : 0.f;
    sx0[tid] = x0; sy0[tid] = y0; sx1[tid] = x1i; sy1[tid] = y1i;
    sw00[tid] = (1.f - ly) * (1.f - lx) * vm;
    sw01[tid] = (1.f - ly) * lx * vm;
    sw10[tid] = ly * (1.f - lx) * vm;
    sw11[tid] = ly * lx * vm;
  }
  __syncthreads();
  const int c8 = (tid & 31) * 8;  // 8 channels per thread (16B loads)
  const int pq = tid >> 5;        // position phase 0..7
  const ushort* base = imgTb + (size_t)sf * 409600 + c8;
  ushort* outp = A + (size_t)r * 12544 + c8;
  for (int p = pq; p < 49; p += 8) {
    const us8v a = *(const us8v*)(base + (size_t)(sy0[p] * 40 + sx0[p]) * 256);
    const us8v b = *(const us8v*)(base + (size_t)(sy0[p] * 40 + sx1[p]) * 256);
    const us8v c = *(const us8v*)(base + (size_t)(sy1[p] * 40 + sx0[p]) * 256);
    const us8v d = *(const us8v*)(base + (size_t)(sy1[p] * 40 + sx1[p]) * 256);
    float w00 = sw00[p], w01 = sw01[p], w10 = sw10[p], w11 = sw11[p];
    us8v o;
#pragma unroll
    for (int k = 0; k < 8; ++k)
      o[k] = f2bf(bf2f(a[k]) * w00 + bf2f(b[k]) * w01 + bf2f(c[k]) * w10 + bf2f(d[k]) * w11);
    *(us8v*)(outp + (size_t)p * 256) = o;
  }
}

// ------- 4. GEMM1: [4096,12544]x[512,12544]^T bf16, BK=64, split-K=7, bf16 partials ------
// LDS swizzle (BK=64, 8 chunks/row): slot s of row R holds global chunk s ^ (R&7).
// Staging instr s: lane tid writes LDS o = s*4096+tid*16 -> row = s*32+(tid>>3),
//   slot = tid&7, so source chunk = (tid&7)^((tid>>3)&7).
// Fragment (k-step h, quad q): wants chunk h*4+q of row (..+r16) -> slot (h*4+q)^(r16&7).
__global__ __launch_bounds__(256) void gemm1_kernel(const ushort* __restrict__ A,
                                                    const ushort* __restrict__ B,
                                                    ushort* __restrict__ P) {
  constexpr int K = 12544;
  constexpr int KS = 1792;  // = K/7, 28 iters of 64
  __shared__ __align__(16) ushort sA[128 * 64];  // 16 KB
  __shared__ __align__(16) ushort sB[128 * 64];  // 16 KB
  const int tid = threadIdx.x;
  const int lane = tid & 63, wave = tid >> 6;
  const int wm = wave >> 1, wn = wave & 1;
  const int r16 = lane & 15, quad = lane >> 4;
  const int r0 = blockIdx.x * 128, c0 = blockIdx.y * 128;
  const int kStart = blockIdx.z * KS, kEnd = kStart + KS;
  const ushort* Ab = A + (size_t)r0 * K;
  const ushort* Bb = B + (size_t)c0 * K;
  const int row8 = tid >> 3;                      // 0..31 (row within 32-row staging slab)
  const int koff = (((tid & 7) ^ (row8 & 7))) * 8;  // swizzled source chunk offset
  const int sw = r16 & 7;
  f32x4 acc[4][4] = {};
  for (int kk = kStart; kk < kEnd; kk += 64) {
    __syncthreads();
#pragma unroll
    for (int s = 0; s < 4; ++s)
      async16(Ab + (size_t)(s * 32 + row8) * K + kk + koff, (char*)sA + s * 4096 + tid * 16);
#pragma unroll
    for (int s = 0; s < 4; ++s)
      async16(Bb + (size_t)(s * 32 + row8) * K + kk + koff, (char*)sB + s * 4096 + tid * 16);
    __syncthreads();
#pragma unroll
    for (int h = 0; h < 2; ++h) {
      const int slot = ((h * 4 + quad) ^ sw) * 8;
      bf16x8 af[4], bfr[4];
#pragma unroll
      for (int i = 0; i < 4; ++i)
        af[i] = *(const bf16x8*)(sA + (wm * 64 + i * 16 + r16) * 64 + slot);
#pragma unroll
      for (int j = 0; j < 4; ++j)
        bfr[j] = *(const bf16x8*)(sB + (wn * 64 + j * 16 + r16) * 64 + slot);
#pragma unroll
      for (int i = 0; i < 4; ++i)
#pragma unroll
        for (int j = 0; j < 4; ++j)
          acc[i][j] = __builtin_amdgcn_mfma_f32_16x16x32_bf16(af[i], bfr[j], acc[i][j], 0, 0, 0);
    }
  }
  ushort* Pz = P + ((size_t)blockIdx.z * 4096 + r0) * 512 + c0;
#pragma unroll
  for (int i = 0; i < 4; ++i)
#pragma unroll
    for (int j = 0; j < 4; ++j)
#pragma unroll
      for (int g = 0; g < 4; ++g)
        Pz[(size_t)(wm * 64 + i * 16 + quad * 4 + g) * 512 + (wn * 64 + j * 16 + r16)] =
            f2bf(acc[i][j][g]);
}

// ------- 5. combine 7 split-K bf16 partials + b1 + BN1 + ReLU -> h1 bf16 -----------------
__global__ __launch_bounds__(256) void combine_kernel(const ushort* __restrict__ P,
                                                      const float* __restrict__ b1,
                                                      const float* __restrict__ g1,
                                                      const float* __restrict__ bt1,
                                                      const float* __restrict__ m1,
                                                      const float* __restrict__ v1,
                                                      ushort* __restrict__ h1) {
  size_t i = (size_t)blockIdx.x * 256 + threadIdx.x;  // exactly 4096*512
  int col = (int)(i & 511);
  float x = 0.f;
#pragma unroll
  for (int z = 0; z < 7; ++z) x += bf2f(P[i + (size_t)z * 2097152]);
  float s = g1[col] * rsqrtf(v1[col] + BN_EPS);
  float val = fmaxf((x + b1[col] - m1[col]) * s + bt1[col], 0.f);
  h1[i] = f2bf(val);
}

// ------- 6. GEMM2 (64x128 tile, BK=64) + b2 + BN2 + ReLU + group-of-8 max -> out ---------
__global__ __launch_bounds__(256) void gemm2_kernel(const ushort* __restrict__ A,
                                                    const ushort* __restrict__ B,
                                                    const float* __restrict__ b2,
                                                    const float* __restrict__ g2,
                                                    const float* __restrict__ bt2,
                                                    const float* __restrict__ m2,
                                                    const float* __restrict__ v2,
                                                    float* __restrict__ out) {
  constexpr int K = 512;
  __shared__ __align__(16) ushort sA[64 * 64];   // 8 KB
  __shared__ __align__(16) ushort sB[128 * 64];  // 16 KB
  __shared__ ushort st[64 * 128];                // post-activation tile for group-max
  const int tid = threadIdx.x;
  const int lane = tid & 63, wave = tid >> 6;
  const int wm = wave >> 1, wn = wave & 1;  // waves: 2 (rows) x 2 (cols)
  const int r16 = lane & 15, quad = lane >> 4;
  const int r0 = blockIdx.x * 64, c0 = blockIdx.y * 128;
  const ushort* Ab = A + (size_t)r0 * K;
  const ushort* Bb = B + (size_t)c0 * K;
  const int row8 = tid >> 3;
  const int koff = (((tid & 7) ^ (row8 & 7))) * 8;
  const int sw = r16 & 7;
  f32x4 acc[2][4] = {};
  for (int kk = 0; kk < K; kk += 64) {
    __syncthreads();
#pragma unroll
    for (int s = 0; s < 2; ++s)
      async16(Ab + (size_t)(s * 32 + row8) * K + kk + koff, (char*)sA + s * 4096 + tid * 16);
#pragma unroll
    for (int s = 0; s < 4; ++s)
      async16(Bb + (size_t)(s * 32 + row8) * K + kk + koff, (char*)sB + s * 4096 + tid * 16);
    __syncthreads();
#pragma unroll
    for (int h = 0; h < 2; ++h) {
      const int slot = ((h * 4 + quad) ^ sw) * 8;
      bf16x8 af[2], bfr[4];
#pragma unroll
      for (int i = 0; i < 2; ++i)
        af[i] = *(const bf16x8*)(sA + (wm * 32 + i * 16 + r16) * 64 + slot);
#pragma unroll
      for (int j = 0; j < 4; ++j)
        bfr[j] = *(const bf16x8*)(sB + (wn * 64 + j * 16 + r16) * 64 + slot);
#pragma unroll
      for (int i = 0; i < 2; ++i)
#pragma unroll
        for (int j = 0; j < 4; ++j)
          acc[i][j] = __builtin_amdgcn_mfma_f32_16x16x32_bf16(af[i], bfr[j], acc[i][j], 0, 0, 0);
    }
  }
  // epilogue: bias + BN + relu, stage to LDS
  float ss[4], tt[4], bbv[4];
#pragma unroll
  for (int j = 0; j < 4; ++j) {
    int c = c0 + wn * 64 + j * 16 + r16;
    float s = g2[c] * rsqrtf(v2[c] + BN_EPS);
    ss[j] = s; tt[j] = bt2[c] - m2[c] * s; bbv[j] = b2[c];
  }
#pragma unroll
  for (int i = 0; i < 2; ++i)
#pragma unroll
    for (int j = 0; j < 4; ++j)
#pragma unroll
      for (int g = 0; g < 4; ++g) {
        int rr = wm * 32 + i * 16 + quad * 4 + g;
        int cc = wn * 64 + j * 16 + r16;
        float x = (acc[i][j][g] + bbv[j]) * ss[j] + tt[j];
        st[rr * 128 + cc] = f2bf(fmaxf(x, 0.f));
      }
  __syncthreads();
  // 64 rows = 8 complete groups of 8; reduce and store (no atomics)
  for (int e = tid; e < 1024; e += 256) {
    int gg = e >> 7, cc = e & 127;
    float m = 0.f;  // relu output >= 0
#pragma unroll
    for (int k = 0; k < 8; ++k) m = fmaxf(m, bf2f(st[(gg * 8 + k) * 128 + cc]));
    out[(size_t)(r0 / 8 + gg) * 512 + c0 + cc] = m;
  }
}

extern "C" void kernel_launch(void* const* d_in, const int* in_sizes, int n_in,
                              void* d_out, int out_size, void* d_ws, size_t ws_size,
                              hipStream_t stream) {
  (void)in_sizes; (void)n_in; (void)out_size; (void)ws_size;
  const float* images = (const float*)d_in[0];
  const int* kf      = (const int*)d_in[1];
  const float* boxes = (const float*)d_in[2];
  const float* w1    = (const float*)d_in[3];
  const float* b1    = (const float*)d_in[4];
  const float* g1    = (const float*)d_in[5];
  const float* bt1   = (const float*)d_in[6];
  const float* m1    = (const float*)d_in[7];
  const float* v1    = (const float*)d_in[8];
  const float* w2    = (const float*)d_in[9];
  const float* b2    = (const float*)d_in[10];
  const float* g2    = (const float*)d_in[11];
  const float* bt2   = (const float*)d_in[12];
  const float* m2    = (const float*)d_in[13];
  const float* v2    = (const float*)d_in[14];
  float* out = (float*)d_out;

  char* ws = (char*)d_ws;
  // layout (bytes):  [ws_size >= 221 MB proven in round 1]
  //   A     @ 0          : 4096*12544*2 = 102,760,448
  //   w1b   @ 102,760,448: 512*12544*2  =  12,845,056
  //   w2b   @ 115,605,504: 512*512*2    =     524,288
  //   imgTb @ 116,129,792: 64*1600*256*2 = 52,428,800   (dead after roi_kernel)
  //   P     @ 116,129,792: 7*4096*512*2 = 29,360,128    (bf16 partials, aliases imgTb)
  //   h1    @ 149,684,224: 4096*512*2   =  4,194,304
  ushort* Abuf  = (ushort*)(ws + 0);
  ushort* w1b   = (ushort*)(ws + 102760448);
  ushort* w2b   = (ushort*)(ws + 115605504);
  ushort* imgTb = (ushort*)(ws + 116129792);
  ushort* P     = (ushort*)(ws + 116129792);
  ushort* h1    = (ushort*)(ws + 149684224);

  hipLaunchKernelGGL(transpose_kernel, dim3(64, 4, 25), dim3(256), 0, stream, images, imgTb);
  hipLaunchKernelGGL(w1_convert, dim3(512), dim3(256), 0, stream, w1, w1b);
  hipLaunchKernelGGL(w2_convert, dim3(1024), dim3(256), 0, stream, w2, w2b);
  hipLaunchKernelGGL(roi_kernel, dim3(4096), dim3(256), 0, stream, imgTb, kf, boxes, Abuf);
  hipLaunchKernelGGL(gemm1_kernel, dim3(32, 4, 7), dim3(256), 0, stream, Abuf, w1b, P);
  hipLaunchKernelGGL(combine_kernel, dim3(8192), dim3(256), 0, stream, P, b1, g1, bt1, m1, v1, h1);
  hipLaunchKernelGGL(gemm2_kernel, dim3(64, 4), dim3(256), 0, stream, h1, w2b, b2, g2, bt2, m2, v2, out);
}

// Round 6
// 353.609 us; speedup vs baseline: 1.7136x; 1.0079x over previous
//
#include <hip/hip_runtime.h>

// NodeEncoder: RoIAlign -> FC1(12544->512)+BN+ReLU -> FC2(512->512)+BN+ReLU -> max over K=8
// F=64 C=256 H=W=40, N=512 K=8 (R=4096), ROI=7, HID=D=512

typedef __bf16 bf16x8 __attribute__((ext_vector_type(8)));
typedef float f32x4 __attribute__((ext_vector_type(4)));
typedef ushort us8v __attribute__((ext_vector_type(8)));

#define BN_EPS 1e-3f

__device__ __forceinline__ ushort f2bf(float f) {
  union { float f; unsigned u; } v; v.f = f;
  unsigned r = (v.u + 0x7FFFu + ((v.u >> 16) & 1u)) >> 16;
  return (ushort)r;
}
__device__ __forceinline__ float bf2f(ushort b) {
  union { unsigned u; float f; } v; v.u = ((unsigned)b) << 16;
  return v.f;
}
__device__ __forceinline__ void async16(const void* g, void* l) {
  __builtin_amdgcn_global_load_lds((const __attribute__((address_space(1))) void*)g,
                                   (__attribute__((address_space(3))) void*)l, 16, 0, 0);
}

// ------- 1. images [64,256,40,40] f32 -> imgTb [64,40,40,256] bf16 -----------------------
// 256ch x 64px tile per block; 4x4 register micro-transpose; wide (b64) LDS only.
// Pitch 260 ushorts (520 B): b64 writes hit 16 distinct banks x4 = optimal; reads same.
__global__ __launch_bounds__(256) void transpose_kernel(const float* __restrict__ img,
                                                        ushort* __restrict__ imgTb) {
  __shared__ ushort lds[64 * 260];  // [pixel][channel], pitch 260
  const int f = blockIdx.x, p0 = blockIdx.y * 64;
  const int tid = threadIdx.x;
  const float* src = img + (size_t)f * 409600 + p0;
#pragma unroll
  for (int m = 0; m < 4; ++m) {
    int g = m * 256 + tid;
    int cg = g >> 4;   // channel group (4 ch), 0..63
    int pg = g & 15;   // pixel group (4 px)
    float4 v[4];
#pragma unroll
    for (int j = 0; j < 4; ++j)
      v[j] = *(const float4*)(src + (size_t)(cg * 4 + j) * 1600 + pg * 4);
#pragma unroll
    for (int i = 0; i < 4; ++i) {
      ushort4 o;
      o.x = f2bf((&v[0].x)[i]);
      o.y = f2bf((&v[1].x)[i]);
      o.z = f2bf((&v[2].x)[i]);
      o.w = f2bf((&v[3].x)[i]);
      *(ushort4*)(&lds[(pg * 4 + i) * 260 + cg * 4]) = o;
    }
  }
  __syncthreads();
  ushort* dst = imgTb + ((size_t)f * 1600 + p0) * 256;
#pragma unroll
  for (int q = 0; q < 8; ++q) {
    int p = q * 8 + (tid >> 5);  // pixel 0..63
    int cg8 = tid & 31;          // 8-channel group
    ushort4 a = *(const ushort4*)(&lds[p * 260 + cg8 * 8]);
    ushort4 b = *(const ushort4*)(&lds[p * 260 + cg8 * 8 + 4]);
    us8v o;
    o[0] = a.x; o[1] = a.y; o[2] = a.z; o[3] = a.w;
    o[4] = b.x; o[5] = b.y; o[6] = b.z; o[7] = b.w;
    *(us8v*)(dst + (size_t)p * 256 + cg8 * 8) = o;  // 512 B/pixel, fully coalesced
  }
}

// ------- 2. w1 [512][256][49] f32 -> w1b [512][49*256] bf16 (k = p*256+c), LDS staged ----
__global__ __launch_bounds__(256) void w1_convert(const float* __restrict__ w1,
                                                  ushort* __restrict__ w1b) {
  __shared__ float t[49 * 257];  // [p][c], pitch 257 floats
  const int o = blockIdx.x;
  const float* src = w1 + (size_t)o * 12544;
  for (int j = threadIdx.x; j < 12544; j += 256) {  // coalesced read, j = c*49+p
    int c = j / 49, p = j - c * 49;
    t[p * 257 + c] = src[j];
  }
  __syncthreads();
  ushort* dst = w1b + (size_t)o * 12544;
  for (int k = threadIdx.x; k < 12544; k += 256) {  // coalesced write, k = p*256+c
    int p = k >> 8, c = k & 255;
    dst[k] = f2bf(t[p * 257 + c]);
  }
}

__global__ __launch_bounds__(256) void w2_convert(const float* __restrict__ w2,
                                                  ushort* __restrict__ w2b) {
  size_t i = (size_t)blockIdx.x * 256 + threadIdx.x;  // exactly 512*512
  w2b[i] = f2bf(w2[i]);
}

// ------- 3. RoIAlign (bf16 image) -> A [4096][12544] bf16, k = (py*7+px)*256 + c ---------
__global__ __launch_bounds__(256) void roi_kernel(const ushort* __restrict__ imgTb,
                                                  const int* __restrict__ kf,
                                                  const float* __restrict__ boxes,
                                                  ushort* __restrict__ A) {
  __shared__ int sy0[49], sx0[49], sy1[49], sx1[49];
  __shared__ float sw00[49], sw01[49], sw10[49], sw11[49];
  __shared__ int sf;
  const int r = blockIdx.x, tid = threadIdx.x;
  if (tid == 0) sf = kf[r];
  if (tid < 49) {
    int py = tid / 7, px = tid % 7;
    float x1 = boxes[r * 4 + 0] * 40.f, y1 = boxes[r * 4 + 1] * 40.f;
    float x2 = boxes[r * 4 + 2] * 40.f, y2 = boxes[r * 4 + 3] * 40.f;
    float bw = (x2 - x1) * (1.f / 7.f), bh = (y2 - y1) * (1.f / 7.f);
    float X = x1 + (px + 0.5f) * bw, Y = y1 + (py + 0.5f) * bh;
    bool valid = (X > -1.f) && (X < 40.f) && (Y > -1.f) && (Y < 40.f);
    float x = fminf(fmaxf(X, 0.f), 39.f), y = fminf(fmaxf(Y, 0.f), 39.f);
    float x0f = floorf(x), y0f = floorf(y);
    int x0 = (int)x0f, y0 = (int)y0f;
    int x1i = min(x0 + 1, 39), y1i = min(y0 + 1, 39);
    float lx = x - x0f, ly = y - y0f;
    float vm = valid ? 1.f : 0.f;
    sx0[tid] = x0; sy0[tid] = y0; sx1[tid] = x1i; sy1[tid] = y1i;
    sw00[tid] = (1.f - ly) * (1.f - lx) * vm;
    sw01[tid] = (1.f - ly) * lx * vm;
    sw10[tid] = ly * (1.f - lx) * vm;
    sw11[tid] = ly * lx * vm;
  }
  __syncthreads();
  const int c8 = (tid & 31) * 8;  // 8 channels per thread (16B loads)
  const int pq = tid >> 5;        // position phase 0..7
  const ushort* base = imgTb + (size_t)sf * 409600 + c8;
  ushort* outp = A + (size_t)r * 12544 + c8;
  for (int p = pq; p < 49; p += 8) {
    const us8v a = *(const us8v*)(base + (size_t)(sy0[p] * 40 + sx0[p]) * 256);
    const us8v b = *(const us8v*)(base + (size_t)(sy0[p] * 40 + sx1[p]) * 256);
    const us8v c = *(const us8v*)(base + (size_t)(sy1[p] * 40 + sx0[p]) * 256);
    const us8v d = *(const us8v*)(base + (size_t)(sy1[p] * 40 + sx1[p]) * 256);
    float w00 = sw00[p], w01 = sw01[p], w10 = sw10[p], w11 = sw11[p];
    us8v o;
#pragma unroll
    for (int k = 0; k < 8; ++k)
      o[k] = f2bf(bf2f(a[k]) * w00 + bf2f(b[k]) * w01 + bf2f(c[k]) * w10 + bf2f(d[k]) * w11);
    *(us8v*)(outp + (size_t)p * 256) = o;
  }
}

// ------- 4. GEMM1: [4096,12544]x[512,12544]^T bf16, BK=64, split-K=7, bf16 partials ------
// LDS swizzle (BK=64, 8 chunks/row): slot s of row R holds global chunk s ^ (R&7).
__global__ __launch_bounds__(256) void gemm1_kernel(const ushort* __restrict__ A,
                                                    const ushort* __restrict__ B,
                                                    ushort* __restrict__ P) {
  constexpr int K = 12544;
  constexpr int KS = 1792;  // = K/7, 28 iters of 64
  __shared__ __align__(16) ushort sA[128 * 64];  // 16 KB
  __shared__ __align__(16) ushort sB[128 * 64];  // 16 KB
  const int tid = threadIdx.x;
  const int lane = tid & 63, wave = tid >> 6;
  const int wm = wave >> 1, wn = wave & 1;
  const int r16 = lane & 15, quad = lane >> 4;
  const int r0 = blockIdx.x * 128, c0 = blockIdx.y * 128;
  const int kStart = blockIdx.z * KS, kEnd = kStart + KS;
  const ushort* Ab = A + (size_t)r0 * K;
  const ushort* Bb = B + (size_t)c0 * K;
  const int row8 = tid >> 3;                        // 0..31
  const int koff = (((tid & 7) ^ (row8 & 7))) * 8;  // swizzled source chunk offset
  const int sw = r16 & 7;
  f32x4 acc[4][4] = {};
  for (int kk = kStart; kk < kEnd; kk += 64) {
    __syncthreads();
#pragma unroll
    for (int s = 0; s < 4; ++s)
      async16(Ab + (size_t)(s * 32 + row8) * K + kk + koff, (char*)sA + s * 4096 + tid * 16);
#pragma unroll
    for (int s = 0; s < 4; ++s)
      async16(Bb + (size_t)(s * 32 + row8) * K + kk + koff, (char*)sB + s * 4096 + tid * 16);
    __syncthreads();
#pragma unroll
    for (int h = 0; h < 2; ++h) {
      const int slot = ((h * 4 + quad) ^ sw) * 8;
      bf16x8 af[4], bfr[4];
#pragma unroll
      for (int i = 0; i < 4; ++i)
        af[i] = *(const bf16x8*)(sA + (wm * 64 + i * 16 + r16) * 64 + slot);
#pragma unroll
      for (int j = 0; j < 4; ++j)
        bfr[j] = *(const bf16x8*)(sB + (wn * 64 + j * 16 + r16) * 64 + slot);
#pragma unroll
      for (int i = 0; i < 4; ++i)
#pragma unroll
        for (int j = 0; j < 4; ++j)
          acc[i][j] = __builtin_amdgcn_mfma_f32_16x16x32_bf16(af[i], bfr[j], acc[i][j], 0, 0, 0);
    }
  }
  ushort* Pz = P + ((size_t)blockIdx.z * 4096 + r0) * 512 + c0;
#pragma unroll
  for (int i = 0; i < 4; ++i)
#pragma unroll
    for (int j = 0; j < 4; ++j)
#pragma unroll
      for (int g = 0; g < 4; ++g)
        Pz[(size_t)(wm * 64 + i * 16 + quad * 4 + g) * 512 + (wn * 64 + j * 16 + r16)] =
            f2bf(acc[i][j][g]);
}

// ------- 5. combine 7 split-K bf16 partials + b1 + BN1 + ReLU -> h1 bf16 -----------------
__global__ __launch_bounds__(256) void combine_kernel(const ushort* __restrict__ P,
                                                      const float* __restrict__ b1,
                                                      const float* __restrict__ g1,
                                                      const float* __restrict__ bt1,
                                                      const float* __restrict__ m1,
                                                      const float* __restrict__ v1,
                                                      ushort* __restrict__ h1) {
  size_t i = (size_t)blockIdx.x * 256 + threadIdx.x;  // exactly 4096*512
  int col = (int)(i & 511);
  float x = 0.f;
#pragma unroll
  for (int z = 0; z < 7; ++z) x += bf2f(P[i + (size_t)z * 2097152]);
  float s = g1[col] * rsqrtf(v1[col] + BN_EPS);
  float val = fmaxf((x + b1[col] - m1[col]) * s + bt1[col], 0.f);
  h1[i] = f2bf(val);
}

// ------- 6. GEMM2 (64x128 tile, BK=64) + b2 + BN2 + ReLU + group-of-8 max -> out ---------
__global__ __launch_bounds__(256) void gemm2_kernel(const ushort* __restrict__ A,
                                                    const ushort* __restrict__ B,
                                                    const float* __restrict__ b2,
                                                    const float* __restrict__ g2,
                                                    const float* __restrict__ bt2,
                                                    const float* __restrict__ m2,
                                                    const float* __restrict__ v2,
                                                    float* __restrict__ out) {
  constexpr int K = 512;
  __shared__ __align__(16) ushort sA[64 * 64];   // 8 KB
  __shared__ __align__(16) ushort sB[128 * 64];  // 16 KB
  __shared__ ushort st[64 * 128];                // post-activation tile for group-max
  const int tid = threadIdx.x;
  const int lane = tid & 63, wave = tid >> 6;
  const int wm = wave >> 1, wn = wave & 1;  // waves: 2 (rows) x 2 (cols)
  const int r16 = lane & 15, quad = lane >> 4;
  const int r0 = blockIdx.x * 64, c0 = blockIdx.y * 128;
  const ushort* Ab = A + (size_t)r0 * K;
  const ushort* Bb = B + (size_t)c0 * K;
  const int row8 = tid >> 3;
  const int koff = (((tid & 7) ^ (row8 & 7))) * 8;
  const int sw = r16 & 7;
  f32x4 acc[2][4] = {};
  for (int kk = 0; kk < K; kk += 64) {
    __syncthreads();
#pragma unroll
    for (int s = 0; s < 2; ++s)
      async16(Ab + (size_t)(s * 32 + row8) * K + kk + koff, (char*)sA + s * 4096 + tid * 16);
#pragma unroll
    for (int s = 0; s < 4; ++s)
      async16(Bb + (size_t)(s * 32 + row8) * K + kk + koff, (char*)sB + s * 4096 + tid * 16);
    __syncthreads();
#pragma unroll
    for (int h = 0; h < 2; ++h) {
      const int slot = ((h * 4 + quad) ^ sw) * 8;
      bf16x8 af[2], bfr[4];
#pragma unroll
      for (int i = 0; i < 2; ++i)
        af[i] = *(const bf16x8*)(sA + (wm * 32 + i * 16 + r16) * 64 + slot);
#pragma unroll
      for (int j = 0; j < 4; ++j)
        bfr[j] = *(const bf16x8*)(sB + (wn * 64 + j * 16 + r16) * 64 + slot);
#pragma unroll
      for (int i = 0; i < 2; ++i)
#pragma unroll
        for (int j = 0; j < 4; ++j)
          acc[i][j] = __builtin_amdgcn_mfma_f32_16x16x32_bf16(af[i], bfr[j], acc[i][j], 0, 0, 0);
    }
  }
  // epilogue: bias + BN + relu, stage to LDS
  float ss[4], tt[4], bbv[4];
#pragma unroll
  for (int j = 0; j < 4; ++j) {
    int c = c0 + wn * 64 + j * 16 + r16;
    float s = g2[c] * rsqrtf(v2[c] + BN_EPS);
    ss[j] = s; tt[j] = bt2[c] - m2[c] * s; bbv[j] = b2[c];
  }
#pragma unroll
  for (int i = 0; i < 2; ++i)
#pragma unroll
    for (int j = 0; j < 4; ++j)
#pragma unroll
      for (int g = 0; g < 4; ++g) {
        int rr = wm * 32 + i * 16 + quad * 4 + g;
        int cc = wn * 64 + j * 16 + r16;
        float x = (acc[i][j][g] + bbv[j]) * ss[j] + tt[j];
        st[rr * 128 + cc] = f2bf(fmaxf(x, 0.f));
      }
  __syncthreads();
  // 64 rows = 8 complete groups of 8; reduce and store (no atomics)
  for (int e = tid; e < 1024; e += 256) {
    int gg = e >> 7, cc = e & 127;
    float m = 0.f;  // relu output >= 0
#pragma unroll
    for (int k = 0; k < 8; ++k) m = fmaxf(m, bf2f(st[(gg * 8 + k) * 128 + cc]));
    out[(size_t)(r0 / 8 + gg) * 512 + c0 + cc] = m;
  }
}

extern "C" void kernel_launch(void* const* d_in, const int* in_sizes, int n_in,
                              void* d_out, int out_size, void* d_ws, size_t ws_size,
                              hipStream_t stream) {
  (void)in_sizes; (void)n_in; (void)out_size; (void)ws_size;
  const float* images = (const float*)d_in[0];
  const int* kf      = (const int*)d_in[1];
  const float* boxes = (const float*)d_in[2];
  const float* w1    = (const float*)d_in[3];
  const float* b1    = (const float*)d_in[4];
  const float* g1    = (const float*)d_in[5];
  const float* bt1   = (const float*)d_in[6];
  const float* m1    = (const float*)d_in[7];
  const float* v1    = (const float*)d_in[8];
  const float* w2    = (const float*)d_in[9];
  const float* b2    = (const float*)d_in[10];
  const float* g2    = (const float*)d_in[11];
  const float* bt2   = (const float*)d_in[12];
  const float* m2    = (const float*)d_in[13];
  const float* v2    = (const float*)d_in[14];
  float* out = (float*)d_out;

  char* ws = (char*)d_ws;
  // layout (bytes):  [ws_size >= 221 MB proven in round 1]
  //   A     @ 0          : 4096*12544*2 = 102,760,448
  //   w1b   @ 102,760,448: 512*12544*2  =  12,845,056
  //   w2b   @ 115,605,504: 512*512*2    =     524,288
  //   imgTb @ 116,129,792: 64*1600*256*2 = 52,428,800   (dead after roi_kernel)
  //   P     @ 116,129,792: 7*4096*512*2 = 29,360,128    (bf16 partials, aliases imgTb)
  //   h1    @ 149,684,224: 4096*512*2   =  4,194,304
  ushort* Abuf  = (ushort*)(ws + 0);
  ushort* w1b   = (ushort*)(ws + 102760448);
  ushort* w2b   = (ushort*)(ws + 115605504);
  ushort* imgTb = (ushort*)(ws + 116129792);
  ushort* P     = (ushort*)(ws + 116129792);
  ushort* h1    = (ushort*)(ws + 149684224);

  hipLaunchKernelGGL(transpose_kernel, dim3(64, 25), dim3(256), 0, stream, images, imgTb);
  hipLaunchKernelGGL(w1_convert, dim3(512), dim3(256), 0, stream, w1, w1b);
  hipLaunchKernelGGL(w2_convert, dim3(1024), dim3(256), 0, stream, w2, w2b);
  hipLaunchKernelGGL(roi_kernel, dim3(4096), dim3(256), 0, stream, imgTb, kf, boxes, Abuf);
  hipLaunchKernelGGL(gemm1_kernel, dim3(32, 4, 7), dim3(256), 0, stream, Abuf, w1b, P);
  hipLaunchKernelGGL(combine_kernel, dim3(8192), dim3(256), 0, stream, P, b1, g1, bt1, m1, v1, h1);
  hipLaunchKernelGGL(gemm2_kernel, dim3(64, 4), dim3(256), 0, stream, h1, w2b, b2, g2, bt2, m2, v2, out);
}